// Round 1
// baseline (670.825 us; speedup 1.0000x reference)
//
#include <hip/hip_runtime.h>

#define TOK 64
#define CDIM 192
#define NH 6
#define HD 32
#define QSCALE 0.17677669529663687f  // 32^-0.5

typedef _Float16 f16x8 __attribute__((ext_vector_type(8)));
typedef _Float16 f16x4 __attribute__((ext_vector_type(4)));
typedef float f32x4 __attribute__((ext_vector_type(4)));

// Load 8 consecutive fp32 from global, convert to fp16 fragment.
__device__ __forceinline__ f16x8 cvt8(const float* __restrict__ p) {
  float4 a = *reinterpret_cast<const float4*>(p);
  float4 c = *reinterpret_cast<const float4*>(p + 4);
  f16x8 r;
  r[0] = (_Float16)a.x; r[1] = (_Float16)a.y; r[2] = (_Float16)a.z; r[3] = (_Float16)a.w;
  r[4] = (_Float16)c.x; r[5] = (_Float16)c.y; r[6] = (_Float16)c.z; r[7] = (_Float16)c.w;
  return r;
}

__device__ __forceinline__ f16x8 ld8(const _Float16* p) {
  return *reinterpret_cast<const f16x8*>(p);
}

// Fused window attention: one block per window (64 tokens), 4 waves.
// LDS buffers use K-blocked panel layout: elem(row, k) at [(k>>3)*ROWS + row]*8 + (k&7)
// so every MFMA fragment read is a contiguous 16B ds_read_b128, conflict-free.
__global__ __launch_bounds__(256, 2) void winattn_kernel(
    const float* __restrict__ x, const float* __restrict__ w_qkv,
    const float* __restrict__ b_qkv, const float* __restrict__ w_proj,
    const float* __restrict__ b_proj, const float* __restrict__ bias_table,
    float* __restrict__ out) {
  __shared__ __align__(16) _Float16 xb[24 * TOK * 8];   // x   [c-panel][n][c&7]
  __shared__ __align__(16) _Float16 qb[4 * TOK * 8];    // q   [d-panel][n][d&7] (scaled)
  __shared__ __align__(16) _Float16 skb[4 * TOK * 8];   // k   [d-panel][n][d&7]
  __shared__ __align__(16) _Float16 vtb[8 * HD * 8];    // v^T [t-panel][d][t&7]
  __shared__ __align__(16) _Float16 pb[8 * TOK * 8];    // P   [j-panel][i][j&7]
  __shared__ __align__(16) _Float16 ob[24 * TOK * 8];   // attn-out [c-panel][n][c&7]
  __shared__ float bias_sm[225 * NH];

  const int tid = threadIdx.x;
  const int w   = tid >> 6;    // wave 0..3
  const int l   = tid & 63;
  const int l15 = l & 15;
  const int lg  = l >> 4;      // 0..3 (k-block group)
  const int b   = blockIdx.x;

  // ---- stage x (fp32 -> fp16 panels) and bias table ----
  const float* xg = x + (size_t)b * (TOK * CDIM);
  for (int i = tid; i < TOK * CDIM / 4; i += 256) {
    int n = i / (CDIM / 4);
    int c = (i % (CDIM / 4)) * 4;
    float4 v = reinterpret_cast<const float4*>(xg)[i];
    f16x4 h4;
    h4[0] = (_Float16)v.x; h4[1] = (_Float16)v.y;
    h4[2] = (_Float16)v.z; h4[3] = (_Float16)v.w;
    *reinterpret_cast<f16x4*>(&xb[((c >> 3) * TOK + n) * 8 + (c & 7)]) = h4;
  }
  for (int i = tid; i < 225 * NH; i += 256) bias_sm[i] = bias_table[i];
  __syncthreads();

  const f32x4 vzero = {0.f, 0.f, 0.f, 0.f};
  const int mt0 = (w & 1) * 2;     // QKV phase: this wave's m-tile base (of 4)
  const int ntb = 3 * (w >> 1);    // QKV phase: this wave's n-tile base (of 6)

  for (int h = 0; h < NH; ++h) {
    // ================= QKV GEMM for head h =================
    // out cols: nt 0,1 -> q(0..31)  nt 2,3 -> k  nt 4,5 -> v
    f32x4 acc[2][3];
#pragma unroll
    for (int mi = 0; mi < 2; ++mi)
#pragma unroll
      for (int j = 0; j < 3; ++j) acc[mi][j] = vzero;

#pragma unroll
    for (int ks = 0; ks < 6; ++ks) {  // K = 192
      f16x8 a0 = ld8(&xb[((ks * 4 + lg) * TOK + (mt0 + 0) * 16 + l15) * 8]);
      f16x8 a1 = ld8(&xb[((ks * 4 + lg) * TOK + (mt0 + 1) * 16 + l15) * 8]);
#pragma unroll
      for (int j = 0; j < 3; ++j) {
        int nt = ntb + j;
        int dg = (nt >> 1) * CDIM + h * HD + (nt & 1) * 16 + l15;  // global qkv out dim
        f16x8 bf = cvt8(w_qkv + (size_t)dg * CDIM + ks * 32 + lg * 8);
        acc[0][j] = __builtin_amdgcn_mfma_f32_16x16x32_f16(a0, bf, acc[0][j], 0, 0, 0);
        acc[1][j] = __builtin_amdgcn_mfma_f32_16x16x32_f16(a1, bf, acc[1][j], 0, 0, 0);
      }
    }
    // epilogue: + b_qkv, scale q, scatter to q/k/v^T panels
#pragma unroll
    for (int j = 0; j < 3; ++j) {
      int nt = ntb + j;
      int part = nt >> 1;                 // 0=q 1=k 2=v
      int dl = (nt & 1) * 16 + l15;       // 0..31 within head
      float bq = b_qkv[part * CDIM + h * HD + dl];
#pragma unroll
      for (int mi = 0; mi < 2; ++mi) {
#pragma unroll
        for (int r = 0; r < 4; ++r) {
          int n = (mt0 + mi) * 16 + lg * 4 + r;  // token
          float v = acc[mi][j][r] + bq;
          if (part == 0)
            qb[((dl >> 3) * TOK + n) * 8 + (dl & 7)] = (_Float16)(v * QSCALE);
          else if (part == 1)
            skb[((dl >> 3) * TOK + n) * 8 + (dl & 7)] = (_Float16)v;
          else
            vtb[((n >> 3) * HD + dl) * 8 + (n & 7)] = (_Float16)v;
        }
      }
    }
    __syncthreads();

    // ================= S = q k^T + bias, softmax -> P =================
    // wave w owns score rows i in [16w, 16w+16)
    f16x8 qf = ld8(&qb[(lg * TOK + w * 16 + l15) * 8]);
    f32x4 s[4];
#pragma unroll
    for (int nt = 0; nt < 4; ++nt) {
      f16x8 kf = ld8(&skb[(lg * TOK + nt * 16 + l15) * 8]);
      s[nt] = __builtin_amdgcn_mfma_f32_16x16x32_f16(qf, kf, vzero, 0, 0, 0);
    }
    // relative-position bias
#pragma unroll
    for (int nt = 0; nt < 4; ++nt) {
      int j = nt * 16 + l15, yj = j >> 3, xj = j & 7;
#pragma unroll
      for (int r = 0; r < 4; ++r) {
        int i = w * 16 + lg * 4 + r, yi = i >> 3, xi = i & 7;
        s[nt][r] += bias_sm[((yi - yj + 7) * 15 + (xi - xj + 7)) * NH + h];
      }
    }
    // per-row softmax: reduce over 4 in-lane n-tiles + 16 lanes
#pragma unroll
    for (int r = 0; r < 4; ++r) {
      float m = fmaxf(fmaxf(s[0][r], s[1][r]), fmaxf(s[2][r], s[3][r]));
#pragma unroll
      for (int off = 1; off < 16; off <<= 1) m = fmaxf(m, __shfl_xor(m, off, 64));
      float e0 = __expf(s[0][r] - m), e1 = __expf(s[1][r] - m);
      float e2 = __expf(s[2][r] - m), e3 = __expf(s[3][r] - m);
      float sum = e0 + e1 + e2 + e3;
#pragma unroll
      for (int off = 1; off < 16; off <<= 1) sum += __shfl_xor(sum, off, 64);
      float inv = 1.f / sum;  // sum >= 1 (max term) -> safe
      int i = w * 16 + lg * 4 + r;
      pb[((2 * 0 + (l15 >> 3)) * TOK + i) * 8 + (l15 & 7)] = (_Float16)(e0 * inv);
      pb[((2 * 1 + (l15 >> 3)) * TOK + i) * 8 + (l15 & 7)] = (_Float16)(e1 * inv);
      pb[((2 * 2 + (l15 >> 3)) * TOK + i) * 8 + (l15 & 7)] = (_Float16)(e2 * inv);
      pb[((2 * 3 + (l15 >> 3)) * TOK + i) * 8 + (l15 & 7)] = (_Float16)(e3 * inv);
    }
    // (no barrier needed: P rows are wave-local; v^T covered by QKV barrier)

    // ================= O_h = P V =================
    f32x4 o[2];
    o[0] = vzero; o[1] = vzero;
#pragma unroll
    for (int ks = 0; ks < 2; ++ks) {  // K = 64 tokens
      f16x8 pf = ld8(&pb[((ks * 4 + lg) * TOK + w * 16 + l15) * 8]);
#pragma unroll
      for (int nt = 0; nt < 2; ++nt) {
        f16x8 vf = ld8(&vtb[((ks * 4 + lg) * HD + nt * 16 + l15) * 8]);
        o[nt] = __builtin_amdgcn_mfma_f32_16x16x32_f16(pf, vf, o[nt], 0, 0, 0);
      }
    }
#pragma unroll
    for (int nt = 0; nt < 2; ++nt) {
      int c = h * HD + nt * 16 + l15;
#pragma unroll
      for (int r = 0; r < 4; ++r) {
        int i = w * 16 + lg * 4 + r;
        ob[((c >> 3) * TOK + i) * 8 + (c & 7)] = (_Float16)o[nt][r];
      }
    }
    __syncthreads();  // protect q/k/v^T (and final ob) for next head / proj
  }

  // ================= projection: out = ob @ w_proj^T + b_proj =================
  // wave w owns n-tiles {w, w+4, w+8} of 12 -> W rows read exactly once per block
  f32x4 pacc[4][3];
#pragma unroll
  for (int mt = 0; mt < 4; ++mt)
#pragma unroll
    for (int j = 0; j < 3; ++j) pacc[mt][j] = vzero;

#pragma unroll
  for (int ks = 0; ks < 6; ++ks) {  // K = 192
    f16x8 af[4];
#pragma unroll
    for (int mt = 0; mt < 4; ++mt)
      af[mt] = ld8(&ob[((ks * 4 + lg) * TOK + mt * 16 + l15) * 8]);
#pragma unroll
    for (int j = 0; j < 3; ++j) {
      int e = (w + 4 * j) * 16 + l15;
      f16x8 bf = cvt8(w_proj + (size_t)e * CDIM + ks * 32 + lg * 8);
#pragma unroll
      for (int mt = 0; mt < 4; ++mt)
        pacc[mt][j] = __builtin_amdgcn_mfma_f32_16x16x32_f16(af[mt], bf, pacc[mt][j], 0, 0, 0);
    }
  }
#pragma unroll
  for (int j = 0; j < 3; ++j) {
    int e = (w + 4 * j) * 16 + l15;
    float bp = b_proj[e];
#pragma unroll
    for (int mt = 0; mt < 4; ++mt) {
#pragma unroll
      for (int r = 0; r < 4; ++r) {
        int n = mt * 16 + lg * 4 + r;
        out[((size_t)b * TOK + n) * CDIM + e] = pacc[mt][j][r] + bp;
      }
    }
  }
}

extern "C" void kernel_launch(void* const* d_in, const int* in_sizes, int n_in,
                              void* d_out, int out_size, void* d_ws, size_t ws_size,
                              hipStream_t stream) {
  const float* x          = (const float*)d_in[0];
  const float* w_qkv      = (const float*)d_in[1];
  const float* b_qkv      = (const float*)d_in[2];
  const float* w_proj     = (const float*)d_in[3];
  const float* b_proj     = (const float*)d_in[4];
  const float* bias_table = (const float*)d_in[5];
  float* out = (float*)d_out;
  int B = in_sizes[0] / (TOK * CDIM);
  hipLaunchKernelGGL(winattn_kernel, dim3(B), dim3(256), 0, stream,
                     x, w_qkv, b_qkv, w_proj, b_proj, bias_table, out);
}

// Round 2
// 266.610 us; speedup vs baseline: 2.5161x; 2.5161x over previous
//
#include <hip/hip_runtime.h>

#define TOK 64
#define CDIM 192
#define NH 6
#define HD 32
#define NWAVE 12
#define THREADS 768
#define QSCALE 0.17677669529663687f  // 32^-0.5
#define W16_BYTES ((110592 + 36864) * 2)

typedef _Float16 f16x8 __attribute__((ext_vector_type(8)));
typedef _Float16 f16x4 __attribute__((ext_vector_type(4)));
typedef float f32x4 __attribute__((ext_vector_type(4)));

__device__ __forceinline__ f16x8 ld8(const _Float16* p) {
  return *reinterpret_cast<const f16x8*>(p);
}

// fp32 -> fp16 fragment (fallback path when d_ws too small for weights)
__device__ __forceinline__ f16x8 cvt8(const float* __restrict__ p) {
  float4 a = *reinterpret_cast<const float4*>(p);
  float4 c = *reinterpret_cast<const float4*>(p + 4);
  f16x8 r;
  r[0] = (_Float16)a.x; r[1] = (_Float16)a.y; r[2] = (_Float16)a.z; r[3] = (_Float16)a.w;
  r[4] = (_Float16)c.x; r[5] = (_Float16)c.y; r[6] = (_Float16)c.z; r[7] = (_Float16)c.w;
  return r;
}

// Prologue: convert w_qkv (576x192) and w_proj (192x192) fp32 -> fp16 into ws.
__global__ void cvt_weights(const float* __restrict__ wq, const float* __restrict__ wp,
                            _Float16* __restrict__ w16) {
  int i = blockIdx.x * 256 + threadIdx.x;  // over float4 chunks: 27648 + 9216
  if (i < 27648) {
    float4 v = reinterpret_cast<const float4*>(wq)[i];
    f16x4 h;
    h[0] = (_Float16)v.x; h[1] = (_Float16)v.y; h[2] = (_Float16)v.z; h[3] = (_Float16)v.w;
    *reinterpret_cast<f16x4*>(w16 + (size_t)i * 4) = h;
  } else if (i < 36864) {
    int j = i - 27648;
    float4 v = reinterpret_cast<const float4*>(wp)[j];
    f16x4 h;
    h[0] = (_Float16)v.x; h[1] = (_Float16)v.y; h[2] = (_Float16)v.z; h[3] = (_Float16)v.w;
    *reinterpret_cast<f16x4*>(w16 + 110592 + (size_t)j * 4) = h;
  }
}

// Fused window attention: 1 block = 1 window, 12 waves, 3 barriers.
//  Phase 1: full QKV GEMM (wave w -> one 16-col tile of each of q/k/v).
//  Phase 2: wave = (head = w>>1, row-half = w&1); swapped QK^T (mfma(k,q))
//           puts a whole score row in-lane -> softmax = in-lane + 2 shuffles.
//  Phase 3: projection, wave = one 16-col e-tile.
// LDS panels: elem(row,k) at [(k>>3)*ROWS + row]*8 + (k&7) -> all MFMA
// fragment reads are contiguous ds_read_b128.
template <bool W16>
__global__ __launch_bounds__(THREADS, 1) void winattn(
    const float* __restrict__ x, const float* __restrict__ w_qkv,
    const float* __restrict__ b_qkv, const float* __restrict__ w_proj,
    const float* __restrict__ b_proj, const float* __restrict__ bias_table,
    const _Float16* __restrict__ w16, float* __restrict__ out) {
  __shared__ __align__(16) _Float16 xob[24 * TOK * 8];   // x panels, then attn-out panels
  __shared__ __align__(16) _Float16 qb[NH * 4 * TOK * 8];   // q  [h][dpanel][tok][8]
  __shared__ __align__(16) _Float16 kb[NH * 4 * TOK * 8];   // k  [h][dpanel][tok][8]
  __shared__ __align__(16) _Float16 vtb[NH * 8 * HD * 8];   // v^T[h][tpanel][d][8]
  __shared__ __align__(16) _Float16 pbw[NWAVE * 16 * TOK];  // P slice per wave [jpanel][i16][8]
  __shared__ float bias_sm[225 * NH];

  const int tid = threadIdx.x;
  const int w   = tid >> 6;   // 0..11
  const int l   = tid & 63;
  const int l15 = l & 15;
  const int lg  = l >> 4;
  const int b   = blockIdx.x;
  const f32x4 vzero = {0.f, 0.f, 0.f, 0.f};

  // ---------------- phase 0: stage x + bias table ----------------
  const float* xg = x + (size_t)b * (TOK * CDIM);
#pragma unroll
  for (int i = tid; i < TOK * CDIM / 4; i += THREADS) {
    int n = i / (CDIM / 4);
    int c = (i % (CDIM / 4)) * 4;
    float4 v = reinterpret_cast<const float4*>(xg)[i];
    f16x4 h4;
    h4[0] = (_Float16)v.x; h4[1] = (_Float16)v.y;
    h4[2] = (_Float16)v.z; h4[3] = (_Float16)v.w;
    *reinterpret_cast<f16x4*>(&xob[((c >> 3) * TOK + n) * 8 + (c & 7)]) = h4;
  }
  for (int i = tid; i < 225 * NH; i += THREADS) bias_sm[i] = bias_table[i];
  __syncthreads();

  // ---------------- phase 1: QKV GEMM (64x576, K=192) ----------------
  const int h   = w >> 1;                    // head
  const int sdl = h * HD + (w & 1) * 16 + l15;  // out-dim within part (0..191)
  f32x4 acc[3][4];
#pragma unroll
  for (int p = 0; p < 3; ++p)
#pragma unroll
    for (int mt = 0; mt < 4; ++mt) acc[p][mt] = vzero;

#pragma unroll
  for (int ks = 0; ks < 6; ++ks) {
    f16x8 a[4];
#pragma unroll
    for (int mt = 0; mt < 4; ++mt)
      a[mt] = ld8(&xob[((ks * 4 + lg) * TOK + mt * 16 + l15) * 8]);
#pragma unroll
    for (int p = 0; p < 3; ++p) {
      int row = p * CDIM + sdl;
      f16x8 bf;
      if constexpr (W16) bf = ld8(w16 + (size_t)row * CDIM + ks * 32 + lg * 8);
      else               bf = cvt8(w_qkv + (size_t)row * CDIM + ks * 32 + lg * 8);
#pragma unroll
      for (int mt = 0; mt < 4; ++mt)
        acc[p][mt] = __builtin_amdgcn_mfma_f32_16x16x32_f16(a[mt], bf, acc[p][mt], 0, 0, 0);
    }
  }
  {  // epilogue: +bias, scale q, scatter panels
    const int hd = (w & 1) * 16 + l15;  // dim within head
    float bq0 = b_qkv[sdl], bq1 = b_qkv[CDIM + sdl], bq2 = b_qkv[2 * CDIM + sdl];
#pragma unroll
    for (int mt = 0; mt < 4; ++mt) {
#pragma unroll
      for (int r = 0; r < 4; ++r) {
        int n = mt * 16 + lg * 4 + r;
        qb[h * 2048 + ((hd >> 3) * TOK + n) * 8 + (hd & 7)] =
            (_Float16)((acc[0][mt][r] + bq0) * QSCALE);
        kb[h * 2048 + ((hd >> 3) * TOK + n) * 8 + (hd & 7)] =
            (_Float16)(acc[1][mt][r] + bq1);
        vtb[h * 2048 + ((n >> 3) * HD + hd) * 8 + (n & 7)] =
            (_Float16)(acc[2][mt][r] + bq2);
      }
    }
  }
  __syncthreads();  // xob (x) dead from here; reused as attn-out panels

  // ---------------- phase 2: attention (wave-private) ----------------
  {
    const int pw = w * (16 * TOK);  // this wave's P slice
#pragma unroll
    for (int ii = 0; ii < 2; ++ii) {
      const int it = (w & 1) * 2 + ii;  // row tile (16 tokens)
      f16x8 qf = ld8(&qb[h * 2048 + (lg * TOK + it * 16 + l15) * 8]);
      f32x4 st[4];
#pragma unroll
      for (int jt = 0; jt < 4; ++jt) {
        f16x8 kf = ld8(&kb[h * 2048 + (lg * TOK + jt * 16 + l15) * 8]);
        // swapped: A=k rows (j), B=q rows (i) -> lane holds S[j=jt*16+lg*4+r][i=it*16+l15]
        st[jt] = __builtin_amdgcn_mfma_f32_16x16x32_f16(kf, qf, vzero, 0, 0, 0);
      }
      const int i = it * 16 + l15, yi = i >> 3, xi = i & 7;
#pragma unroll
      for (int jt = 0; jt < 4; ++jt) {
#pragma unroll
        for (int r = 0; r < 4; ++r) {
          int j = jt * 16 + lg * 4 + r, yj = j >> 3, xj = j & 7;
          st[jt][r] += bias_sm[((yi - yj + 7) * 15 + (xi - xj + 7)) * NH + h];
        }
      }
      // softmax over row i: 16 in-lane values + lanes differing in lg (xor 16,32)
      float m = st[0][0];
#pragma unroll
      for (int jt = 0; jt < 4; ++jt)
#pragma unroll
        for (int r = 0; r < 4; ++r) m = fmaxf(m, st[jt][r]);
      m = fmaxf(m, __shfl_xor(m, 16, 64));
      m = fmaxf(m, __shfl_xor(m, 32, 64));
      float e[4][4], sum = 0.f;
#pragma unroll
      for (int jt = 0; jt < 4; ++jt)
#pragma unroll
        for (int r = 0; r < 4; ++r) { e[jt][r] = __expf(st[jt][r] - m); sum += e[jt][r]; }
      sum += __shfl_xor(sum, 16, 64);
      sum += __shfl_xor(sum, 32, 64);
      float inv = 1.f / sum;
      // packed P writes: j group jt*16+lg*4..+3 -> panel [(j>>3)*16 + i16]
#pragma unroll
      for (int jt = 0; jt < 4; ++jt) {
        f16x4 pk;
#pragma unroll
        for (int r = 0; r < 4; ++r) pk[r] = (_Float16)(e[jt][r] * inv);
        *reinterpret_cast<f16x4*>(
            &pbw[pw + ((jt * 2 + (lg >> 1)) * 16 + l15) * 8 + (lg & 1) * 4]) = pk;
      }
      // PV: O[16 x 32] = P[16 x 64] * V[64 x 32]
      f32x4 o[2] = {vzero, vzero};
#pragma unroll
      for (int ks = 0; ks < 2; ++ks) {
        f16x8 pf = ld8(&pbw[pw + ((ks * 4 + lg) * 16 + l15) * 8]);
#pragma unroll
        for (int nt = 0; nt < 2; ++nt) {
          f16x8 vf = ld8(&vtb[h * 2048 + ((ks * 4 + lg) * HD + nt * 16 + l15) * 8]);
          o[nt] = __builtin_amdgcn_mfma_f32_16x16x32_f16(pf, vf, o[nt], 0, 0, 0);
        }
      }
#pragma unroll
      for (int nt = 0; nt < 2; ++nt) {
        int c = h * HD + nt * 16 + l15;
#pragma unroll
        for (int r = 0; r < 4; ++r) {
          int i2 = it * 16 + lg * 4 + r;
          xob[((c >> 3) * TOK + i2) * 8 + (c & 7)] = (_Float16)o[nt][r];
        }
      }
    }
  }
  __syncthreads();

  // ---------------- phase 3: projection (64x192, K=192) ----------------
  {
    const int e = w * 16 + l15;  // output channel
    f32x4 pacc[4];
#pragma unroll
    for (int mt = 0; mt < 4; ++mt) pacc[mt] = vzero;
#pragma unroll
    for (int ks = 0; ks < 6; ++ks) {
      f16x8 bf;
      if constexpr (W16) bf = ld8(w16 + 110592 + (size_t)e * CDIM + ks * 32 + lg * 8);
      else               bf = cvt8(w_proj + (size_t)e * CDIM + ks * 32 + lg * 8);
#pragma unroll
      for (int mt = 0; mt < 4; ++mt) {
        f16x8 a = ld8(&xob[((ks * 4 + lg) * TOK + mt * 16 + l15) * 8]);
        pacc[mt] = __builtin_amdgcn_mfma_f32_16x16x32_f16(a, bf, pacc[mt], 0, 0, 0);
      }
    }
    float bp = b_proj[e];
#pragma unroll
    for (int mt = 0; mt < 4; ++mt) {
#pragma unroll
      for (int r = 0; r < 4; ++r) {
        int n = mt * 16 + lg * 4 + r;
        out[((size_t)b * TOK + n) * CDIM + e] = pacc[mt][r] + bp;
      }
    }
  }
}

extern "C" void kernel_launch(void* const* d_in, const int* in_sizes, int n_in,
                              void* d_out, int out_size, void* d_ws, size_t ws_size,
                              hipStream_t stream) {
  const float* x          = (const float*)d_in[0];
  const float* w_qkv      = (const float*)d_in[1];
  const float* b_qkv      = (const float*)d_in[2];
  const float* w_proj     = (const float*)d_in[3];
  const float* b_proj     = (const float*)d_in[4];
  const float* bias_table = (const float*)d_in[5];
  float* out = (float*)d_out;
  int B = in_sizes[0] / (TOK * CDIM);

  if (ws_size >= (size_t)W16_BYTES) {
    _Float16* w16 = (_Float16*)d_ws;
    hipLaunchKernelGGL(cvt_weights, dim3(144), dim3(256), 0, stream, w_qkv, w_proj, w16);
    hipLaunchKernelGGL(winattn<true>, dim3(B), dim3(THREADS), 0, stream,
                       x, w_qkv, b_qkv, w_proj, b_proj, bias_table, w16, out);
  } else {
    hipLaunchKernelGGL(winattn<false>, dim3(B), dim3(THREADS), 0, stream,
                       x, w_qkv, b_qkv, w_proj, b_proj, bias_table,
                       (const _Float16*)nullptr, out);
  }
}